// Round 9
// baseline (257.536 us; speedup 1.0000x reference)
//
#include <hip/hip_runtime.h>

#define BB 32
#define TT 128
#define PP 512
#define DD 300
#define KT 10      // K chunks of 32 (KP = 320 = 300 data + bias slot + zeros)
#define NX 7168    // P * 14: full column set, native 14-stride scan layout
#define AT 256     // A tiles (4096/16)
#define BT 448     // B tiles (7168/16)
#define NEG -1e30f

typedef _Float16 half8 __attribute__((ext_vector_type(8)));
typedef float floatx4 __attribute__((ext_vector_type(4)));

__device__ __forceinline__ void async_load16(const void* g, void* l) {
    __builtin_amdgcn_global_load_lds(
        (const __attribute__((address_space(1))) void*)g,
        (__attribute__((address_space(3))) void*)l, 16, 0, 0);
}

__device__ __forceinline__ floatx4 mfma16(half8 a, half8 b, floatx4 c) {
    return __builtin_amdgcn_mfma_f32_16x16x32_f16(a, b, c, 0, 0, 0);
}

// ---------------------------------------------------------------------------
// Pack into MFMA-fragment-blocked layout + f16 Dekker split (R0/R7 version:
// 16-row tiles, 32-k chunks). Also zeroes the scan-done counter for this
// iteration (pack precedes scan in stream order).
// ---------------------------------------------------------------------------
__global__ __launch_bounds__(256) void pack_kernel(
    const int* __restrict__ tokens, const float* __restrict__ emb,
    const float* __restrict__ diags, const float* __restrict__ bias,
    _Float16* __restrict__ AhP, _Float16* __restrict__ AlP,
    _Float16* __restrict__ BhP, _Float16* __restrict__ BlP,
    unsigned* __restrict__ done_cnt)
{
    const int idx = blockIdx.x * 256 + threadIdx.x;
    if (idx == 0) *done_cnt = 0u;      // visible to scan via kernel boundary
    if (idx >= (AT + BT) * KT * 64) return;
    const int chunk = idx >> 6;
    const int ln = idx & 63;

    const float* src;
    float kslot;
    _Float16 *dh, *dl;
    int kt;
    if (chunk < AT * KT) {
        const int mt = chunk / KT; kt = chunk - mt * KT;
        const int m = mt * 16 + (ln & 15);
        src = emb + (size_t)tokens[m] * DD;
        kslot = 1.0f;
        dh = AhP + (size_t)chunk * 512 + ln * 8;
        dl = AlP + (size_t)chunk * 512 + ln * 8;
    } else {
        const int c2 = chunk - AT * KT;
        const int nt = c2 / KT; kt = c2 - nt * KT;
        const int n = nt * 16 + (ln & 15);       // srow = n directly
        src = diags + (size_t)n * DD;
        kslot = bias[n];
        dh = BhP + (size_t)c2 * 512 + ln * 8;
        dl = BlP + (size_t)c2 * 512 + ln * 8;
    }

    const int k0 = kt * 32 + (ln >> 4) * 8;
    float v[8];
    if (k0 + 8 <= DD) {
        float4 a = *(const float4*)(src + k0);
        float4 b = *(const float4*)(src + k0 + 4);
        v[0] = a.x; v[1] = a.y; v[2] = a.z; v[3] = a.w;
        v[4] = b.x; v[5] = b.y; v[6] = b.z; v[7] = b.w;
    } else {
        #pragma unroll
        for (int i = 0; i < 8; ++i) {
            const int k = k0 + i;
            v[i] = (k < DD) ? src[k] : (k == DD ? kslot : 0.f);
        }
    }
    half8 h, l;
    #pragma unroll
    for (int i = 0; i < 8; ++i) {
        h[i] = (_Float16)v[i];
        l[i] = (_Float16)((v[i] - (float)h[i]) * 4096.f);
    }
    *(half8*)dh = h;
    *(half8*)dl = l;
}

// ---------------------------------------------------------------------------
// GEMM (R9 = R7 proven 64x128 geometry + th1 dead-tile guards).
// C[m][n] = sum_k A[m][k]*B[n][k] (bias folded into k=300).
// R8 post-mortem: 32x32 shape cut ILP (8 chains vs 32) -> dep-stalled; the
// 16x16 R7 config (59.2us) is the anchor. R9 touches ONLY the th=1 blocks:
// th=0 blocks (rows t 0..63, always fully live since dl >= 64) keep the
// VERBATIM R7 loop; th=1 blocks (rows 64..127, ~50% dead on average) get
// wave-uniform guards g0/g1 around the two MFMA triples — at 64-VGPR
// pressure (R7) the R2 spill trap doesn't apply, and the th0 hot path's
// schedule cannot be perturbed. Live-tile MFMA order identical -> live C
// bit-identical. Epilogue store guard unchanged (covers both paths).
// ---------------------------------------------------------------------------
__global__ __launch_bounds__(256, 4) void gemm_kernel(
    const _Float16* __restrict__ AhP, const _Float16* __restrict__ AlP,
    const _Float16* __restrict__ BhP, const _Float16* __restrict__ BlP,
    const int* __restrict__ doc_lens,
    float* __restrict__ C)
{
    __shared__ __align__(16) _Float16 Bs[2][2][8][512];  // [dbuf][h/l][ntile][frag]

    const int tid = threadIdx.x;
    const int w = tid >> 6, ln = tid & 63;
    const int n0t = blockIdx.x * 8, m0t = blockIdx.y * 4;
    const int wm = w & 1, wn = w >> 1;

    const int b  = blockIdx.y >> 1;        // batch element
    const int th = blockIdx.y & 1;         // t-half: rows th*64 .. th*64+63
    const int dl = doc_lens[b];            // in [64, 128]
    if (th == 1 && dl <= 64) return;       // entire block dead (uniform exit)

    floatx4 acc0[2][4], acc1[2][4];
    #pragma unroll
    for (int i = 0; i < 2; ++i)
        #pragma unroll
        for (int j = 0; j < 4; ++j) {
            acc0[i][j] = (floatx4){0.f, 0.f, 0.f, 0.f};
            acc1[i][j] = (floatx4){0.f, 0.f, 0.f, 0.f};
        }

    half8 ah[2][2], al[2][2];

    auto loadA = [&](int kt, int pb) {
        #pragma unroll
        for (int i = 0; i < 2; ++i) {
            const size_t ch = ((size_t)(m0t + wm * 2 + i) * KT + kt) * 512 + ln * 8;
            ah[pb][i] = *(const half8*)(AhP + ch);
            al[pb][i] = *(const half8*)(AlP + ch);
        }
    };
    auto stageB = [&](int kt, int buf) {
        #pragma unroll
        for (int s = 0; s < 2; ++s) {
            const int nt = w + s * 4;   // wave w stages ntiles {w, w+4}
            const size_t ch = ((size_t)(n0t + nt) * KT + kt) * 512 + ln * 8;
            async_load16(BhP + ch, &Bs[buf][0][nt][0]);
            async_load16(BlP + ch, &Bs[buf][1][nt][0]);
        }
    };

    stageB(0, 0);
    loadA(0, 0);
    __syncthreads();

    if (th == 0) {
        // ---- verbatim R7 K-loop: all rows live, no guards ----
        #pragma unroll
        for (int kt = 0; kt < KT; ++kt) {
            const int cb = kt & 1, nb = cb ^ 1;
            if (kt + 1 < KT) {
                loadA(kt + 1, nb);
                stageB(kt + 1, nb);
            }
            #pragma unroll
            for (int j = 0; j < 4; ++j) {
                const half8 bh = *(const half8*)&Bs[cb][0][wn * 4 + j][ln * 8];
                const half8 bl = *(const half8*)&Bs[cb][1][wn * 4 + j][ln * 8];
                #pragma unroll
                for (int i = 0; i < 2; ++i) {
                    acc0[i][j] = mfma16(ah[cb][i], bh, acc0[i][j]);
                    acc1[i][j] = mfma16(ah[cb][i], bl, acc1[i][j]);
                    acc1[i][j] = mfma16(al[cb][i], bh, acc1[i][j]);
                }
            }
            __syncthreads();
        }
    } else {
        // ---- th=1: guard dead 16-row tiles (tile wm*2+i live iff < nlive) ----
        const int nlive = ((dl - 64) + 15) >> 4;   // 1..4 (dl > 64 here)
        const bool g0 = (wm * 2 + 0) < nlive;
        const bool g1 = (wm * 2 + 1) < nlive;
        #pragma unroll
        for (int kt = 0; kt < KT; ++kt) {
            const int cb = kt & 1, nb = cb ^ 1;
            if (kt + 1 < KT) {
                loadA(kt + 1, nb);
                stageB(kt + 1, nb);
            }
            #pragma unroll
            for (int j = 0; j < 4; ++j) {
                const half8 bh = *(const half8*)&Bs[cb][0][wn * 4 + j][ln * 8];
                const half8 bl = *(const half8*)&Bs[cb][1][wn * 4 + j][ln * 8];
                if (g0) {
                    acc0[0][j] = mfma16(ah[cb][0], bh, acc0[0][j]);
                    acc1[0][j] = mfma16(ah[cb][0], bl, acc1[0][j]);
                    acc1[0][j] = mfma16(al[cb][0], bh, acc1[0][j]);
                }
                if (g1) {
                    acc0[1][j] = mfma16(ah[cb][1], bh, acc0[1][j]);
                    acc1[1][j] = mfma16(ah[cb][1], bl, acc1[1][j]);
                    acc1[1][j] = mfma16(al[cb][1], bh, acc1[1][j]);
                }
            }
            __syncthreads();
        }
    }

    // epilogue: C/D layout col(n)=lane&15, row(m)=(lane>>4)*4+reg.
    // store guard: tile i covers t in [th*64+(wm*2+i)*16, +16); dead iff
    // its t0 >= dl (scan never reads those rows).
    #pragma unroll
    for (int j = 0; j < 4; ++j) {
        const int n = (n0t + wn * 4 + j) * 16 + (ln & 15);
        #pragma unroll
        for (int i = 0; i < 2; ++i) {
            if (th * 64 + (wm * 2 + i) * 16 < dl) {
                const int mb = (m0t + wm * 2 + i) * 16 + (ln >> 4) * 4;
                #pragma unroll
                for (int r = 0; r < 4; ++r)
                    C[(size_t)(mb + r) * NX + n] =
                        acc0[i][j][r] + acc1[i][j][r] * (1.0f / 4096.0f);
            }
        }
    }
}

// ---------------------------------------------------------------------------
// Max-sum scan (proven structure) + fused finalize in the LAST block.
// Scan part unchanged. After storing scores, each block signals a device
// counter (release: __syncthreads + __threadfence + atomicAdd). The block
// whose atomicAdd returns 255 is last: all 256 blocks' scores are written
// and fenced; it re-reads scores with agent-scope atomic loads (coherent
// across per-XCD L2s) and computes BatchNorm + sign(relu) + final linear
// with its single 64-lane wave. No spinning -> no deadlock possible.
// ---------------------------------------------------------------------------
__global__ __launch_bounds__(64) void scan_kernel(
    const float* __restrict__ ts,
    const float* __restrict__ epsilons,
    const int* __restrict__ doc_lens,
    float* __restrict__ scores,
    unsigned* __restrict__ done_cnt,
    const float* __restrict__ bn_w,
    const float* __restrict__ bn_b,
    const float* __restrict__ fw,
    const float* __restrict__ fb,
    float* __restrict__ out)
{
    const int b = blockIdx.x;
    const int p = blockIdx.y * 64 + threadIdx.x;
    const int dl = doc_lens[b];   // in [64, 128]

    float e[6];
    #pragma unroll
    for (int i = 0; i < 6; ++i) e[i] = epsilons[p * 6 + i];

    const float* base = ts + (size_t)b * TT * NX + p * 14;

    float h0 = 0.f, h1 = NEG, h2 = NEG, h3 = NEG, h4 = NEG, h5 = NEG, h6 = NEG;
    float sc = NEG;
    const bool end5 = (p < 256);

    float2 buf[4][7];

    auto load = [&](int slot, int t) {
        const float2* s = (const float2*)(base + (size_t)t * NX);
        #pragma unroll
        for (int i = 0; i < 7; ++i) buf[slot][i] = s[i];
    };
    auto step = [&](int slot) {
        const float2* v = buf[slot];
        float ae0 = h0;
        float ae1 = fmaxf(h1, h0 + e[0]);
        float ae2 = fmaxf(h2, h1 + e[1]);
        float ae3 = fmaxf(h3, h2 + e[2]);
        float ae4 = fmaxf(h4, h3 + e[3]);
        float ae5 = fmaxf(h5, h4 + e[4]);
        float ae6 = fmaxf(h6, h5 + e[5]);
        h0 = fmaxf(0.f,            ae0 + v[0].x);
        h1 = fmaxf(ae0 + v[3].y,   ae1 + v[0].y);
        h2 = fmaxf(ae1 + v[4].x,   ae2 + v[1].x);
        h3 = fmaxf(ae2 + v[4].y,   ae3 + v[1].y);
        h4 = fmaxf(ae3 + v[5].x,   ae4 + v[2].x);
        h5 = fmaxf(ae4 + v[5].y,   ae5 + v[2].y);
        h6 = fmaxf(ae5 + v[6].x,   ae6 + v[3].x);
        sc = fmaxf(sc, end5 ? h5 : h6);   // every executed step has t < dl
    };

    #pragma unroll
    for (int j = 0; j < 4; ++j) load(j, j);

    int tb = 0;
    for (; tb + 4 <= dl; tb += 4) {
        #pragma unroll
        for (int j = 0; j < 4; ++j) {
            step(j);
            const int t = tb + j + 4;
            load(j, t > 127 ? 127 : t);   // clamp: slots past dl never consumed
        }
    }
    const int rem = dl - tb;       // 0..3, block-uniform
    #pragma unroll
    for (int j = 0; j < 3; ++j)
        if (j < rem) step(j);

    scores[p * BB + b] = sc;

    // ---- completion signal ----
    __syncthreads();                        // order all 64 stores before signal
    __threadfence();                        // release to device scope
    int last = 0;
    if (threadIdx.x == 0)
        last = (atomicAdd(done_cnt, 1u) == (unsigned)(BB * (PP / 64)) - 1u);
    last = __shfl(last, 0);
    if (!last) return;
    __threadfence();                        // acquire

    // ---- finalize: BatchNorm (batch stats) + sign(relu) + final linear ----
    const int t = threadIdx.x;              // 64 lanes; lane handles 8 patterns
    float s0[32], s1[32];
    #pragma unroll
    for (int i = 0; i < 32; ++i) { s0[i] = 0.f; s1[i] = 0.f; }

    #pragma unroll
    for (int pi = 0; pi < 8; ++pi) {
        const int q = pi * 64 + t;
        float x[32];
        #pragma unroll
        for (int i = 0; i < 32; ++i)
            x[i] = __hip_atomic_load(&scores[q * 32 + i],
                                     __ATOMIC_RELAXED, __HIP_MEMORY_SCOPE_AGENT);
        float mean = 0.f;
        #pragma unroll
        for (int i = 0; i < 32; ++i) mean += x[i];
        mean *= (1.f / 32.f);
        float var = 0.f;
        #pragma unroll
        for (int i = 0; i < 32; ++i) { const float d = x[i] - mean; var = fmaf(d, d, var); }
        var *= (1.f / 32.f);
        const float scale = (1.f / sqrtf(var + 1e-5f)) * bn_w[q];
        const float shift = bn_b[q];
        const float w0 = fw[q], w1 = fw[PP + q];
        #pragma unroll
        for (int i = 0; i < 32; ++i) {
            const float v = (x[i] - mean) * scale + shift;
            if (v > 0.f) { s0[i] += w0; s1[i] += w1; }
        }
    }
    #pragma unroll
    for (int i = 0; i < 32; ++i) {
        #pragma unroll
        for (int o = 32; o; o >>= 1) {
            s0[i] += __shfl_xor(s0[i], o);
            s1[i] += __shfl_xor(s1[i], o);
        }
    }
    if (t == 0) {
        const float b0 = fb[0], b1 = fb[1];
        #pragma unroll
        for (int i = 0; i < 32; ++i) {
            out[2 * i]     = s0[i] + b0;
            out[2 * i + 1] = s1[i] + b1;
        }
    }
}

// ---------------------------------------------------------------------------
extern "C" void kernel_launch(void* const* d_in, const int* in_sizes, int n_in,
                              void* d_out, int out_size, void* d_ws, size_t ws_size,
                              hipStream_t stream) {
    const int*   tokens   = (const int*)d_in[0];
    const int*   doc_lens = (const int*)d_in[1];
    const float* emb      = (const float*)d_in[2];
    const float* diags    = (const float*)d_in[3];
    const float* bias     = (const float*)d_in[4];
    const float* eps      = (const float*)d_in[5];
    const float* bnw      = (const float*)d_in[6];
    const float* bnb      = (const float*)d_in[7];
    const float* fw       = (const float*)d_in[8];
    const float* fb       = (const float*)d_in[9];
    float* out = (float*)d_out;

    float* ts       = (float*)d_ws;                  // [4096][7168] = 117.4 MB
    float* scores   = ts + (size_t)4096 * NX;        // [512][32]
    unsigned* cnt   = (unsigned*)(scores + PP * BB); // scan-done counter
    _Float16* AhP   = (_Float16*)(scores + PP * BB + 16);  // 16B-aligned
    _Float16* AlP = AhP + (size_t)AT * KT * 512;
    _Float16* BhP = AlP + (size_t)AT * KT * 512;
    _Float16* BlP = BhP + (size_t)BT * KT * 512;

    pack_kernel<<<(AT + BT) * KT * 64 / 256, 256, 0, stream>>>(
        tokens, emb, diags, bias, AhP, AlP, BhP, BlP, cnt);
    gemm_kernel<<<dim3(BT / 8, AT / 4), 256, 0, stream>>>(
        AhP, AlP, BhP, BlP, doc_lens, ts);
    scan_kernel<<<dim3(BB, PP / 64), 64, 0, stream>>>(
        ts, eps, doc_lens, scores, cnt, bnw, bnb, fw, fb, out);
}